// Round 11
// baseline (5838.988 us; speedup 1.0000x reference)
//
#include <hip/hip_runtime.h>
#include <hip/hip_bf16.h>
#include <hip/hip_fp16.h>

// ===========================================================================
// CSR build (multi-block scan; deterministic via per-row sort)
// ===========================================================================
__global__ void hist_kernel(const int* __restrict__ rows, int* __restrict__ counts, int E) {
    int i = blockIdx.x * blockDim.x + threadIdx.x;
    if (i < E) atomicAdd(&counts[rows[i]], 1);
}

__global__ void chunk_sum_kernel(const int* __restrict__ counts, int* __restrict__ chunk_sums, int V) {
    __shared__ int sh[256];
    int t = threadIdx.x;
    int i = blockIdx.x * 256 + t;
    sh[t] = (i < V) ? counts[i] : 0;
    __syncthreads();
    for (int st = 128; st > 0; st >>= 1) {
        if (t < st) sh[t] += sh[t + st];
        __syncthreads();
    }
    if (t == 0) chunk_sums[blockIdx.x] = sh[0];
}

__global__ void scan_chunks_kernel(int* __restrict__ cs, int n) {
    __shared__ int wsum[4];
    int t = threadIdx.x, lane = t & 63, w = t >> 6;
    int orig = (t < n) ? cs[t] : 0;
    int x = orig;
    #pragma unroll
    for (int d = 1; d < 64; d <<= 1) {
        int y = __shfl_up(x, d);
        if (lane >= d) x += y;
    }
    if (lane == 63) wsum[w] = x;
    __syncthreads();
    int wo = 0;
    for (int j = 0; j < w; ++j) wo += wsum[j];
    if (t < n) cs[t] = wo + x - orig;     // exclusive
}

__global__ void scan_final_kernel(const int* __restrict__ counts, const int* __restrict__ chunk_off,
                                  int* __restrict__ row_ptr, int V) {
    __shared__ int wsum[4];
    int t = threadIdx.x, lane = t & 63, w = t >> 6;
    int i = blockIdx.x * 256 + t;
    int x = (i < V) ? counts[i] : 0;
    #pragma unroll
    for (int d = 1; d < 64; d <<= 1) {
        int y = __shfl_up(x, d);
        if (lane >= d) x += y;
    }
    if (lane == 63) wsum[w] = x;
    __syncthreads();
    int wo = 0;
    for (int j = 0; j < w; ++j) wo += wsum[j];
    if (i < V) row_ptr[i + 1] = chunk_off[blockIdx.x] + wo + x;
    if (i == 0) row_ptr[0] = 0;
}

__global__ void init_cursor_kernel(const int* __restrict__ row_ptr, int* __restrict__ cursor, int V) {
    int i = blockIdx.x * blockDim.x + threadIdx.x;
    if (i < V) cursor[i] = row_ptr[i];
}

__global__ void scatter_kernel(const int* __restrict__ rows, const int* __restrict__ cols,
                               const float* __restrict__ vals, int* __restrict__ cursor,
                               int* __restrict__ cols_s, float* __restrict__ vals_s, int E) {
    int i = blockIdx.x * blockDim.x + threadIdx.x;
    if (i < E) {
        int r = rows[i];
        int p = atomicAdd(&cursor[r], 1);
        cols_s[p] = cols[i];
        vals_s[p] = vals[i];
    }
}

// canonical per-row order: insertion sort by (col, val-bits). Makes CSR
// bitwise-deterministic regardless of scatter's atomic ordering.
__global__ void sort_rows_kernel(const int* __restrict__ row_ptr, int* cols, float* vals, int V) {
    int v = blockIdx.x * blockDim.x + threadIdx.x;
    if (v >= V) return;
    int e0 = row_ptr[v], e1 = row_ptr[v + 1];
    for (int i = e0 + 1; i < e1; ++i) {
        int c = cols[i];
        unsigned xb = __float_as_uint(vals[i]);
        int j = i - 1;
        while (j >= e0) {
            int cj = cols[j];
            unsigned vj = __float_as_uint(vals[j]);
            if (cj > c || (cj == c && vj > xb)) {
                cols[j + 1] = cj; vals[j + 1] = __uint_as_float(vj);
                --j;
            } else break;
        }
        cols[j + 1] = c;
        vals[j + 1] = __uint_as_float(xb);
    }
}

// ===========================================================================
// transpose input (B,16,V) fp32 -> (V, B*16) fp16
// ===========================================================================
__global__ void transpose_in_kernel(const float* __restrict__ x, __half* __restrict__ X, int V) {
    int total = V * 128;
    for (int i = blockIdx.x * blockDim.x + threadIdx.x; i < total; i += gridDim.x * blockDim.x) {
        int v = i >> 7;
        int t = i & 127;          // t = b*16 + c
        X[i] = __float2half(x[t * V + v]);
    }
}

// ===========================================================================
// SpMM: one wave per node, lane owns VPT half2, unroll 8.
//   dst[v,:] = sum_e vals[e]*src[cols[e],:]        (prev == null)
//   dst[v,:] = 2*that - prev[v,:]                  (prev != null)
// dst always distinct from src/prev in the schedule.
// ===========================================================================
template <int VPT> struct PackT;
template <> struct PackT<1> { using T = float;  };
template <> struct PackT<2> { using T = float2; };
template <> struct PackT<4> { using T = float4; };

template <int VPT>
__global__ __launch_bounds__(256) void spmm2_kernel(
    const int* __restrict__ row_ptr, const int* __restrict__ cols,
    const float* __restrict__ vals, const __half2* __restrict__ src,
    __half2* dst, const __half2* prev, int V) {
    using T = typename PackT<VPT>::T;
    union U { T raw; __half2 h[VPT]; };
    int lane = threadIdx.x & 63;
    int v = (blockIdx.x << 2) | (threadIdx.x >> 6);
    if (v >= V) return;
    const int W = VPT * 64;
    const size_t row = (size_t)v * W + lane * VPT;

    float pr[2 * VPT];
    bool hasp = (prev != nullptr);
    if (hasp) {
        U pv; pv.raw = *(const T*)(prev + row);
        #pragma unroll
        for (int j = 0; j < VPT; ++j) {
            float2 f = __half22float2(pv.h[j]);
            pr[2 * j] = f.x; pr[2 * j + 1] = f.y;
        }
    }
    float acc[2 * VPT];
    #pragma unroll
    for (int j = 0; j < 2 * VPT; ++j) acc[j] = 0.f;

    int e0 = row_ptr[v], e1 = row_ptr[v + 1];
    int e = e0;
    for (; e + 8 <= e1; e += 8) {
        int   c[8]; float w[8]; U g[8];
        #pragma unroll
        for (int k = 0; k < 8; ++k) { c[k] = cols[e + k]; w[k] = vals[e + k]; }
        #pragma unroll
        for (int k = 0; k < 8; ++k)
            g[k].raw = *(const T*)(src + (size_t)c[k] * W + lane * VPT);
        #pragma unroll
        for (int k = 0; k < 8; ++k) {
            #pragma unroll
            for (int j = 0; j < VPT; ++j) {
                float2 f = __half22float2(g[k].h[j]);
                acc[2*j] += w[k] * f.x; acc[2*j+1] += w[k] * f.y;
            }
        }
    }
    for (; e + 4 <= e1; e += 4) {
        int   c[4]; float w[4]; U g[4];
        #pragma unroll
        for (int k = 0; k < 4; ++k) { c[k] = cols[e + k]; w[k] = vals[e + k]; }
        #pragma unroll
        for (int k = 0; k < 4; ++k)
            g[k].raw = *(const T*)(src + (size_t)c[k] * W + lane * VPT);
        #pragma unroll
        for (int k = 0; k < 4; ++k) {
            #pragma unroll
            for (int j = 0; j < VPT; ++j) {
                float2 f = __half22float2(g[k].h[j]);
                acc[2*j] += w[k] * f.x; acc[2*j+1] += w[k] * f.y;
            }
        }
    }
    for (; e < e1; ++e) {
        int c = cols[e]; float wv = vals[e];
        U g; g.raw = *(const T*)(src + (size_t)c * W + lane * VPT);
        #pragma unroll
        for (int j = 0; j < VPT; ++j) {
            float2 f = __half22float2(g.h[j]);
            acc[2*j] += wv * f.x; acc[2*j+1] += wv * f.y;
        }
    }
    if (hasp) {
        #pragma unroll
        for (int j = 0; j < 2 * VPT; ++j) acc[j] = 2.f * acc[j] - pr[j];
    }
    U o;
    #pragma unroll
    for (int j = 0; j < VPT; ++j) o.h[j] = __floats2half2_rn(acc[2*j], acc[2*j+1]);
    *(T*)(dst + row) = o.raw;
}

// ===========================================================================
// combine v3: out = f( sum_k T_k @ W_k + bias [+ res] [+ sc @ Wsc] )
// Thread = TWO consecutive (node,batch) rows -> doubles FMA per W broadcast
// (halves per-wave scalar W streaming, the round-10 stall source).
// T rows loaded as float4 chunks (16B) feeding unrolled 8xCOUT FMA bursts.
// Per-row accumulation order identical to round 10 (bitwise-stable).
// NOT __restrict__ on T*/res/sc/out: out may alias an input; each thread
// owns its rows and reads fully before writing.
// ===========================================================================
template <int CIN, int COUT>
__global__ __launch_bounds__(256) void combine_kernel(
    const __half* T0, const __half* T1, const __half* T2, const __half* T3,
    const float* __restrict__ W, const float* __restrict__ bias,
    const __half* res, const __half* sc, const float* __restrict__ Wsc,
    __half* out, int relu, int V) {
    const int CSC = 32;
    union U4 { float4 raw; __half2 h[4]; };
    int g = blockIdx.x * 256 + threadIdx.x;
    int r0 = 2 * g;
    if (r0 >= V * 8) return;
    int n = r0 >> 3, b = r0 & 7;          // rows (n,b) and (n,b+1), b even
    size_t ib = (size_t)n * 8 * CIN + (size_t)b * CIN;

    float acc0[COUT], acc1[COUT];
    #pragma unroll
    for (int c = 0; c < COUT; ++c) {
        float bb = bias ? bias[c] : 0.f;
        acc0[c] = bb; acc1[c] = bb;
    }

    const __half* Ts[4] = {T0, T1, T2, T3};
    #pragma unroll
    for (int k = 0; k < 4; ++k) {
        const float4* rp0 = (const float4*)(Ts[k] + ib);
        const float4* rp1 = (const float4*)(Ts[k] + ib + CIN);
        const float* Wk = W + (size_t)k * CIN * COUT;
        for (int c4 = 0; c4 < CIN / 8; ++c4) {
            U4 x0, x1;
            x0.raw = rp0[c4];
            x1.raw = rp1[c4];
            #pragma unroll
            for (int s = 0; s < 4; ++s) {
                int q = c4 * 4 + s;
                float2 a0 = __half22float2(x0.h[s]);
                float2 a1 = __half22float2(x1.h[s]);
                const float* w0 = Wk + (2 * q) * COUT;
                const float* w1 = Wk + (2 * q + 1) * COUT;
                #pragma unroll
                for (int c = 0; c < COUT; ++c) {
                    float wv0 = w0[c], wv1 = w1[c];
                    acc0[c] = fmaf(a0.x, wv0, acc0[c]);
                    acc0[c] = fmaf(a0.y, wv1, acc0[c]);
                    acc1[c] = fmaf(a1.x, wv0, acc1[c]);
                    acc1[c] = fmaf(a1.y, wv1, acc1[c]);
                }
            }
        }
    }
    if (sc) {
        size_t sb = (size_t)n * 8 * CSC + (size_t)b * CSC;
        const float4* sp0 = (const float4*)(sc + sb);
        const float4* sp1 = (const float4*)(sc + sb + CSC);
        for (int c4 = 0; c4 < CSC / 8; ++c4) {
            U4 x0, x1;
            x0.raw = sp0[c4];
            x1.raw = sp1[c4];
            #pragma unroll
            for (int s = 0; s < 4; ++s) {
                int q = c4 * 4 + s;
                float2 a0 = __half22float2(x0.h[s]);
                float2 a1 = __half22float2(x1.h[s]);
                const float* w0 = Wsc + (2 * q) * COUT;
                const float* w1 = Wsc + (2 * q + 1) * COUT;
                #pragma unroll
                for (int c = 0; c < COUT; ++c) {
                    float wv0 = w0[c], wv1 = w1[c];
                    acc0[c] = fmaf(a0.x, wv0, acc0[c]);
                    acc0[c] = fmaf(a0.y, wv1, acc0[c]);
                    acc1[c] = fmaf(a1.x, wv0, acc1[c]);
                    acc1[c] = fmaf(a1.y, wv1, acc1[c]);
                }
            }
        }
    }
    size_t ob = (size_t)n * 8 * COUT + (size_t)b * COUT;
    if (res) {
        const __half2* rr0 = (const __half2*)(res + ob);
        const __half2* rr1 = (const __half2*)(res + ob + COUT);
        #pragma unroll
        for (int c = 0; c < COUT / 2; ++c) {
            float2 f0 = __half22float2(rr0[c]);
            float2 f1 = __half22float2(rr1[c]);
            acc0[2*c] += f0.x; acc0[2*c+1] += f0.y;
            acc1[2*c] += f1.x; acc1[2*c+1] += f1.y;
        }
    }
    if (relu) {
        #pragma unroll
        for (int c = 0; c < COUT; ++c) {
            acc0[c] = fmaxf(acc0[c], 0.f);
            acc1[c] = fmaxf(acc1[c], 0.f);
        }
    }
    __half2* ro0 = (__half2*)(out + ob);
    __half2* ro1 = (__half2*)(out + ob + COUT);
    #pragma unroll
    for (int c = 0; c < COUT / 2; ++c) {
        ro0[c] = __floats2half2_rn(acc0[2*c], acc0[2*c+1]);
        ro1[c] = __floats2half2_rn(acc1[2*c], acc1[2*c+1]);
    }
}

// ===========================================================================
// BatchNorm: two-stage deterministic stats (no float atomics), SB=1024 blocks
// ===========================================================================
__global__ void bn_stats_part_kernel(const __half* __restrict__ x, int C, int relu_in,
                                     float* __restrict__ part, size_t N) {
    __shared__ float s_sum[256];
    __shared__ float s_sq[256];
    int t = threadIdx.x;
    size_t i0 = (size_t)blockIdx.x * 256 + t;
    size_t step = (size_t)gridDim.x * 256;
    float s = 0.f, q = 0.f;
    for (size_t i = i0; i < N; i += step) {
        float v = __half2float(x[i]);
        if (relu_in) v = fmaxf(v, 0.f);
        s += v; q += v * v;
    }
    s_sum[t] = s; s_sq[t] = q;
    __syncthreads();
    for (int st = 128; st >= C; st >>= 1) {
        if (t < st) { s_sum[t] += s_sum[t + st]; s_sq[t] += s_sq[t + st]; }
        __syncthreads();
    }
    if (t < C) {
        part[blockIdx.x * 128 + t]     = s_sum[t];
        part[blockIdx.x * 128 + C + t] = s_sq[t];
    }
}

__global__ void bn_reduce_kernel(const float* __restrict__ part, int nblk,
                                 const float* __restrict__ g, const float* __restrict__ be,
                                 float* __restrict__ ss, int C, float invN) {
    int c = threadIdx.x;
    if (c < C) {
        float s = 0.f, q = 0.f;
        for (int b = 0; b < nblk; ++b) {        // fixed order -> deterministic
            s += part[b * 128 + c];
            q += part[b * 128 + C + c];
        }
        float m = s * invN;
        float var = q * invN - m * m;
        float sc = g[c] * rsqrtf(var + 1e-5f);
        ss[c] = sc;
        ss[C + c] = be[c] - m * sc;
    }
}

// in-place: x = f(x)*a + b, f = relu if relu_in  (half2-vectorized)
__global__ void affine_h_kernel(__half* x, const float* __restrict__ ss, int C,
                                int relu_in, size_t N2) {
    size_t stride = (size_t)gridDim.x * blockDim.x;
    __half2* x2 = (__half2*)x;
    for (size_t i = (size_t)blockIdx.x * blockDim.x + threadIdx.x; i < N2; i += stride) {
        int c0 = (int)((2 * i) & (size_t)(C - 1));
        float2 f = __half22float2(x2[i]);
        if (relu_in) { f.x = fmaxf(f.x, 0.f); f.y = fmaxf(f.y, 0.f); }
        f.x = f.x * ss[c0] + ss[C + c0];
        f.y = f.y * ss[c0 + 1] + ss[C + c0 + 1];
        x2[i] = __floats2half2_rn(f.x, f.y);
    }
}

// ===========================================================================
// head: partial max over node slices + int-atomicMax (valid: values >= 0),
// then log_softmax (fp32 out)
// ===========================================================================
__global__ void maxpool_h_kernel(const __half* __restrict__ x, float* pooled, int V, int NS) {
    __shared__ float red[256];
    int o = blockIdx.x % 80;
    int slice = blockIdx.x / 80;
    int v0 = (int)((long long)V * slice / NS);
    int v1 = (int)((long long)V * (slice + 1) / NS);
    float m = 0.f;
    for (int v = v0 + threadIdx.x; v < v1; v += 256)
        m = fmaxf(m, __half2float(x[(size_t)v * 80 + o]));
    red[threadIdx.x] = m;
    __syncthreads();
    for (int st = 128; st > 0; st >>= 1) {
        if (threadIdx.x < st) red[threadIdx.x] = fmaxf(red[threadIdx.x], red[threadIdx.x + st]);
        __syncthreads();
    }
    if (threadIdx.x == 0) atomicMax((int*)&pooled[o], __float_as_int(red[0]));
}

__global__ void lsm_kernel(const float* __restrict__ pooled, float* __restrict__ out) {
    int b = threadIdx.x;
    if (b < 8) {
        float m = -1e30f;
        for (int c = 0; c < 10; ++c) m = fmaxf(m, pooled[b * 10 + c]);
        float s = 0.f;
        for (int c = 0; c < 10; ++c) s += expf(pooled[b * 10 + c] - m);
        float l = logf(s);
        for (int c = 0; c < 10; ++c)
            out[b * 10 + c] = pooled[b * 10 + c] - m - l;
    }
}

__global__ void encode_kernel(float* out, float val) {
    int i = threadIdx.x;
    if (i < 80) out[i] = val;
}

// ===========================================================================
// entry
// ===========================================================================
extern "C" void kernel_launch(void* const* d_in, const int* in_sizes, int n_in,
                              void* d_out, int out_size, void* d_ws, size_t ws_size,
                              hipStream_t stream) {
    (void)in_sizes; (void)n_in; (void)out_size;
    const int V = 50000, E = 800000;
    const int NCH = (V + 255) / 256;
    const int SB = 1024;                      // bn stage-1 blocks
    const int NS = 8;                         // maxpool node slices

    auto al = [](size_t x) { return (x + 255) & ~(size_t)255; };
    const size_t FB = al((size_t)V * 512 * sizeof(__half));     // 51.2 MB
    const size_t need = 5 * FB + al((V + 1) * 4) + al(V * 4) + al(E * 4) + al(E * 4)
                      + al((size_t)SB * 128 * 4) + al(8 * 128 * 4) + al(80 * 4) + al(NCH * 4);
    if (ws_size < need) {
        encode_kernel<<<1, 128, 0, stream>>>((float*)d_out, (float)(ws_size >> 20));
        return;
    }

    const float* x_in = (const float*)d_in[0];
    const int* rows   = (const int*)d_in[1];
    const int* colsi  = (const int*)d_in[2];
    const float* lvals = (const float*)d_in[3];
    const float* W_in = (const float*)d_in[4];
    const float* b_in = (const float*)d_in[5];
    const float* g1a = (const float*)d_in[6],  *be1a = (const float*)d_in[7];
    const float* W1a = (const float*)d_in[8],  *b1a  = (const float*)d_in[9];
    const float* g1b = (const float*)d_in[10], *be1b = (const float*)d_in[11];
    const float* W1b = (const float*)d_in[12], *b1b  = (const float*)d_in[13];
    const float* g2a = (const float*)d_in[14], *be2a = (const float*)d_in[15];
    const float* W2a = (const float*)d_in[16], *b2a  = (const float*)d_in[17];
    const float* g2b = (const float*)d_in[18], *be2b = (const float*)d_in[19];
    const float* W2b = (const float*)d_in[20], *b2b  = (const float*)d_in[21];
    const float* W2s = (const float*)d_in[22];
    const float* g3a = (const float*)d_in[23], *be3a = (const float*)d_in[24];
    const float* W3a = (const float*)d_in[25], *b3a  = (const float*)d_in[26];
    const float* g3b = (const float*)d_in[27], *be3b = (const float*)d_in[28];
    const float* W3b = (const float*)d_in[29], *b3b  = (const float*)d_in[30];
    const float* g_o = (const float*)d_in[31], *be_o = (const float*)d_in[32];
    const float* W_o = (const float*)d_in[33], *b_o  = (const float*)d_in[34];

    char* wp = (char*)d_ws;
    auto take = [&](size_t bytes) -> void* { void* p = (void*)wp; wp += al(bytes); return p; };
    __half* P0 = (__half*)take(FB);
    __half* P1 = (__half*)take(FB);
    __half* P2 = (__half*)take(FB);
    __half* P3 = (__half*)take(FB);
    __half* P4 = (__half*)take(FB);
    int* row_ptr  = (int*)take((V + 1) * sizeof(int));
    int* cursor   = (int*)take(V * sizeof(int));
    int* cols_s   = (int*)take(E * sizeof(int));
    float* vals_s = (float*)take(E * sizeof(float));
    float* part   = (float*)take((size_t)SB * 128 * sizeof(float));
    float* aff    = (float*)take(8 * 128 * sizeof(float));
    float* pooled = (float*)take(80 * sizeof(float));
    int* chunks   = (int*)take(NCH * sizeof(int));

    // Launch-state independence: every ws buffer except cursor/pooled is
    // fully written before it is read (verified per buffer); cursor needs
    // zeros for hist atomics, pooled needs zeros for atomicMax.
    hipMemsetAsync(cursor, 0, V * sizeof(int), stream);
    hipMemsetAsync(pooled, 0, 80 * sizeof(float), stream);

    // ---- CSR build (+canonical row order) + input transpose ----
    hist_kernel<<<(E + 255) / 256, 256, 0, stream>>>(rows, cursor, E);
    chunk_sum_kernel<<<NCH, 256, 0, stream>>>(cursor, chunks, V);
    scan_chunks_kernel<<<1, 256, 0, stream>>>(chunks, NCH);
    scan_final_kernel<<<NCH, 256, 0, stream>>>(cursor, chunks, row_ptr, V);
    init_cursor_kernel<<<(V + 255) / 256, 256, 0, stream>>>(row_ptr, cursor, V);
    scatter_kernel<<<(E + 255) / 256, 256, 0, stream>>>(rows, colsi, lvals, cursor, cols_s, vals_s, E);
    sort_rows_kernel<<<(V + 255) / 256, 256, 0, stream>>>(row_ptr, cols_s, vals_s, V);
    transpose_in_kernel<<<4096, 256, 0, stream>>>(x_in, P0, V);

    // ---- helpers ----
    auto spmm = [&](const __half* src, __half* dst, const __half* prev, int C) {
        int grid = (V + 3) / 4;
        if (C == 16)
            spmm2_kernel<1><<<grid, 256, 0, stream>>>(row_ptr, cols_s, vals_s,
                (const __half2*)src, (__half2*)dst, (const __half2*)prev, V);
        else if (C == 32)
            spmm2_kernel<2><<<grid, 256, 0, stream>>>(row_ptr, cols_s, vals_s,
                (const __half2*)src, (__half2*)dst, (const __half2*)prev, V);
        else
            spmm2_kernel<4><<<grid, 256, 0, stream>>>(row_ptr, cols_s, vals_s,
                (const __half2*)src, (__half2*)dst, (const __half2*)prev, V);
    };
    const int MG2 = (V * 8 / 2 + 255) / 256;
    auto comb = [&](const __half* T0, const __half* T1, const __half* T2, const __half* T3,
                    int Cin, int Cout, const float* W, const float* bias,
                    const __half* res, const __half* sc, const float* Wsc,
                    __half* out, int relu) {
        if (Cin == 16 && Cout == 32)
            combine_kernel<16, 32><<<MG2, 256, 0, stream>>>(T0, T1, T2, T3, W, bias, res, sc, Wsc, out, relu, V);
        else if (Cin == 32 && Cout == 32)
            combine_kernel<32, 32><<<MG2, 256, 0, stream>>>(T0, T1, T2, T3, W, bias, res, sc, Wsc, out, relu, V);
        else if (Cin == 32 && Cout == 64)
            combine_kernel<32, 64><<<MG2, 256, 0, stream>>>(T0, T1, T2, T3, W, bias, res, sc, Wsc, out, relu, V);
        else if (Cin == 64 && Cout == 64)
            combine_kernel<64, 64><<<MG2, 256, 0, stream>>>(T0, T1, T2, T3, W, bias, res, sc, Wsc, out, relu, V);
        else
            combine_kernel<64, 10><<<MG2, 256, 0, stream>>>(T0, T1, T2, T3, W, bias, res, sc, Wsc, out, relu, V);
    };
    auto stats = [&](const __half* xb, int C, int relu, int slot, const float* g, const float* be) {
        bn_stats_part_kernel<<<SB, 256, 0, stream>>>(xb, C, relu, part, (size_t)V * 8 * C);
        bn_reduce_kernel<<<1, 64, 0, stream>>>(part, SB, g, be, aff + slot * 128, C,
                                               1.f / ((float)V * 8.f));
    };
    auto affine = [&](__half* xb, int C, int relu, int slot) {
        affine_h_kernel<<<2048, 256, 0, stream>>>(xb, aff + slot * 128, C, relu,
                                                  (size_t)V * 4 * C);
    };
    const __half* NH = nullptr;
    const float*  NF = nullptr;

    // ---- conv_in: x=P0 (16ch) -> relu(cheb+b) -> P4 (32ch) ----
    spmm(P0, P1, nullptr, 16);              // T1
    spmm(P1, P2, P0, 16);                   // T2
    spmm(P2, P3, P1, 16);                   // T3
    comb(P0, P1, P2, P3, 16, 32, W_in, b_in, NH, NH, NF, P4, 1);

    // ---- block 1 (X=P4, 32ch, identity shortcut) ----
    stats(P4, 32, 0, 0, g1a, be1a);
    affine(P4, 32, 0, 0);                   // P4 = xn
    spmm(P4, P0, nullptr, 32);
    spmm(P0, P1, P4, 32);
    spmm(P1, P2, P0, 32);
    comb(P4, P0, P1, P2, 32, 32, W1a, b1a, NH, NH, NF, P0, 0);   // out_a = P0
    stats(P0, 32, 1, 1, g1b, be1b);
    affine(P0, 32, 1, 1);                   // P0 = y
    spmm(P0, P1, nullptr, 32);
    spmm(P1, P2, P0, 32);
    spmm(P2, P3, P1, 32);
    comb(P0, P1, P2, P3, 32, 32, W1b, b1b, P4, NH, NF, P4, 1);   // P4 = block1 out

    // ---- block 2 (X=P4, 32ch -> 64ch, W2s shortcut) ----
    stats(P4, 32, 0, 2, g2a, be2a);
    affine(P4, 32, 0, 2);                   // P4 = xn (32ch)
    spmm(P4, P0, nullptr, 32);
    spmm(P0, P1, P4, 32);
    spmm(P1, P2, P0, 32);
    comb(P4, P0, P1, P2, 32, 64, W2a, b2a, NH, NH, NF, P3, 0);   // out_a = P3 (64ch)
    stats(P3, 64, 1, 3, g2b, be2b);
    affine(P3, 64, 1, 3);                   // P3 = y
    spmm(P3, P0, nullptr, 64);
    spmm(P0, P1, P3, 64);
    spmm(P1, P2, P0, 64);
    comb(P3, P0, P1, P2, 64, 64, W2b, b2b, NH, P4, W2s, P0, 1);  // P0 = block2 out

    // ---- block 3 (X=P0, 64ch, identity shortcut) ----
    stats(P0, 64, 0, 4, g3a, be3a);
    affine(P0, 64, 0, 4);                   // P0 = xn
    spmm(P0, P1, nullptr, 64);
    spmm(P1, P2, P0, 64);
    spmm(P2, P3, P1, 64);
    comb(P0, P1, P2, P3, 64, 64, W3a, b3a, NH, NH, NF, P1, 0);   // out_a = P1
    stats(P1, 64, 1, 5, g3b, be3b);
    affine(P1, 64, 1, 5);                   // P1 = y
    spmm(P1, P2, nullptr, 64);
    spmm(P2, P3, P1, 64);
    spmm(P3, P4, P2, 64);
    comb(P1, P2, P3, P4, 64, 64, W3b, b3b, P0, NH, NF, P1, 1);   // P1 = block3 out

    // ---- head: bn -> relu(cheb 64->10) -> maxpool -> log_softmax ----
    stats(P1, 64, 0, 6, g_o, be_o);
    affine(P1, 64, 0, 6);                   // P1 = bn(x)
    spmm(P1, P0, nullptr, 64);
    spmm(P0, P2, P1, 64);
    spmm(P2, P3, P0, 64);
    comb(P1, P0, P2, P3, 64, 10, W_o, b_o, NH, NH, NF, P4, 1);   // P4 = 80-wide logits
    maxpool_h_kernel<<<80 * NS, 256, 0, stream>>>(P4, pooled, V, NS);
    lsm_kernel<<<1, 64, 0, stream>>>(pooled, (float*)d_out);
}

// Round 12
// 4584.224 us; speedup vs baseline: 1.2737x; 1.2737x over previous
//
#include <hip/hip_runtime.h>
#include <hip/hip_bf16.h>
#include <hip/hip_fp16.h>

// ===========================================================================
// CSR build (multi-block scan; deterministic via per-row sort)
// ===========================================================================
__global__ void hist_kernel(const int* __restrict__ rows, int* __restrict__ counts, int E) {
    int i = blockIdx.x * blockDim.x + threadIdx.x;
    if (i < E) atomicAdd(&counts[rows[i]], 1);
}

__global__ void chunk_sum_kernel(const int* __restrict__ counts, int* __restrict__ chunk_sums, int V) {
    __shared__ int sh[256];
    int t = threadIdx.x;
    int i = blockIdx.x * 256 + t;
    sh[t] = (i < V) ? counts[i] : 0;
    __syncthreads();
    for (int st = 128; st > 0; st >>= 1) {
        if (t < st) sh[t] += sh[t + st];
        __syncthreads();
    }
    if (t == 0) chunk_sums[blockIdx.x] = sh[0];
}

__global__ void scan_chunks_kernel(int* __restrict__ cs, int n) {
    __shared__ int wsum[4];
    int t = threadIdx.x, lane = t & 63, w = t >> 6;
    int orig = (t < n) ? cs[t] : 0;
    int x = orig;
    #pragma unroll
    for (int d = 1; d < 64; d <<= 1) {
        int y = __shfl_up(x, d);
        if (lane >= d) x += y;
    }
    if (lane == 63) wsum[w] = x;
    __syncthreads();
    int wo = 0;
    for (int j = 0; j < w; ++j) wo += wsum[j];
    if (t < n) cs[t] = wo + x - orig;     // exclusive
}

__global__ void scan_final_kernel(const int* __restrict__ counts, const int* __restrict__ chunk_off,
                                  int* __restrict__ row_ptr, int V) {
    __shared__ int wsum[4];
    int t = threadIdx.x, lane = t & 63, w = t >> 6;
    int i = blockIdx.x * 256 + t;
    int x = (i < V) ? counts[i] : 0;
    #pragma unroll
    for (int d = 1; d < 64; d <<= 1) {
        int y = __shfl_up(x, d);
        if (lane >= d) x += y;
    }
    if (lane == 63) wsum[w] = x;
    __syncthreads();
    int wo = 0;
    for (int j = 0; j < w; ++j) wo += wsum[j];
    if (i < V) row_ptr[i + 1] = chunk_off[blockIdx.x] + wo + x;
    if (i == 0) row_ptr[0] = 0;
}

__global__ void init_cursor_kernel(const int* __restrict__ row_ptr, int* __restrict__ cursor, int V) {
    int i = blockIdx.x * blockDim.x + threadIdx.x;
    if (i < V) cursor[i] = row_ptr[i];
}

__global__ void scatter_kernel(const int* __restrict__ rows, const int* __restrict__ cols,
                               const float* __restrict__ vals, int* __restrict__ cursor,
                               int* __restrict__ cols_s, float* __restrict__ vals_s, int E) {
    int i = blockIdx.x * blockDim.x + threadIdx.x;
    if (i < E) {
        int r = rows[i];
        int p = atomicAdd(&cursor[r], 1);
        cols_s[p] = cols[i];
        vals_s[p] = vals[i];
    }
}

// canonical per-row order: insertion sort by (col, val-bits). Makes CSR
// bitwise-deterministic regardless of scatter's atomic ordering.
__global__ void sort_rows_kernel(const int* __restrict__ row_ptr, int* cols, float* vals, int V) {
    int v = blockIdx.x * blockDim.x + threadIdx.x;
    if (v >= V) return;
    int e0 = row_ptr[v], e1 = row_ptr[v + 1];
    for (int i = e0 + 1; i < e1; ++i) {
        int c = cols[i];
        unsigned xb = __float_as_uint(vals[i]);
        int j = i - 1;
        while (j >= e0) {
            int cj = cols[j];
            unsigned vj = __float_as_uint(vals[j]);
            if (cj > c || (cj == c && vj > xb)) {
                cols[j + 1] = cj; vals[j + 1] = __uint_as_float(vj);
                --j;
            } else break;
        }
        cols[j + 1] = c;
        vals[j + 1] = __uint_as_float(xb);
    }
}

// ===========================================================================
// transpose input (B,16,V) fp32 -> (V, B*16) fp16
// ===========================================================================
__global__ void transpose_in_kernel(const float* __restrict__ x, __half* __restrict__ X, int V) {
    int total = V * 128;
    for (int i = blockIdx.x * blockDim.x + threadIdx.x; i < total; i += gridDim.x * blockDim.x) {
        int v = i >> 7;
        int t = i & 127;          // t = b*16 + c
        X[i] = __float2half(x[t * V + v]);
    }
}

// ===========================================================================
// SpMM: one wave per node, lane owns VPT half2, unroll 8.
//   dst[v,:] = sum_e vals[e]*src[cols[e],:]        (prev == null)
//   dst[v,:] = 2*that - prev[v,:]                  (prev != null)
// dst always distinct from src/prev in the schedule.
// ===========================================================================
template <int VPT> struct PackT;
template <> struct PackT<1> { using T = float;  };
template <> struct PackT<2> { using T = float2; };
template <> struct PackT<4> { using T = float4; };

template <int VPT>
__global__ __launch_bounds__(256) void spmm2_kernel(
    const int* __restrict__ row_ptr, const int* __restrict__ cols,
    const float* __restrict__ vals, const __half2* __restrict__ src,
    __half2* dst, const __half2* prev, int V) {
    using T = typename PackT<VPT>::T;
    union U { T raw; __half2 h[VPT]; };
    int lane = threadIdx.x & 63;
    int v = (blockIdx.x << 2) | (threadIdx.x >> 6);
    if (v >= V) return;
    const int W = VPT * 64;
    const size_t row = (size_t)v * W + lane * VPT;

    float pr[2 * VPT];
    bool hasp = (prev != nullptr);
    if (hasp) {
        U pv; pv.raw = *(const T*)(prev + row);
        #pragma unroll
        for (int j = 0; j < VPT; ++j) {
            float2 f = __half22float2(pv.h[j]);
            pr[2 * j] = f.x; pr[2 * j + 1] = f.y;
        }
    }
    float acc[2 * VPT];
    #pragma unroll
    for (int j = 0; j < 2 * VPT; ++j) acc[j] = 0.f;

    int e0 = row_ptr[v], e1 = row_ptr[v + 1];
    int e = e0;
    for (; e + 8 <= e1; e += 8) {
        int   c[8]; float w[8]; U g[8];
        #pragma unroll
        for (int k = 0; k < 8; ++k) { c[k] = cols[e + k]; w[k] = vals[e + k]; }
        #pragma unroll
        for (int k = 0; k < 8; ++k)
            g[k].raw = *(const T*)(src + (size_t)c[k] * W + lane * VPT);
        #pragma unroll
        for (int k = 0; k < 8; ++k) {
            #pragma unroll
            for (int j = 0; j < VPT; ++j) {
                float2 f = __half22float2(g[k].h[j]);
                acc[2*j] += w[k] * f.x; acc[2*j+1] += w[k] * f.y;
            }
        }
    }
    for (; e + 4 <= e1; e += 4) {
        int   c[4]; float w[4]; U g[4];
        #pragma unroll
        for (int k = 0; k < 4; ++k) { c[k] = cols[e + k]; w[k] = vals[e + k]; }
        #pragma unroll
        for (int k = 0; k < 4; ++k)
            g[k].raw = *(const T*)(src + (size_t)c[k] * W + lane * VPT);
        #pragma unroll
        for (int k = 0; k < 4; ++k) {
            #pragma unroll
            for (int j = 0; j < VPT; ++j) {
                float2 f = __half22float2(g[k].h[j]);
                acc[2*j] += w[k] * f.x; acc[2*j+1] += w[k] * f.y;
            }
        }
    }
    for (; e < e1; ++e) {
        int c = cols[e]; float wv = vals[e];
        U g; g.raw = *(const T*)(src + (size_t)c * W + lane * VPT);
        #pragma unroll
        for (int j = 0; j < VPT; ++j) {
            float2 f = __half22float2(g.h[j]);
            acc[2*j] += wv * f.x; acc[2*j+1] += wv * f.y;
        }
    }
    if (hasp) {
        #pragma unroll
        for (int j = 0; j < 2 * VPT; ++j) acc[j] = 2.f * acc[j] - pr[j];
    }
    U o;
    #pragma unroll
    for (int j = 0; j < VPT; ++j) o.h[j] = __floats2half2_rn(acc[2*j], acc[2*j+1]);
    *(T*)(dst + row) = o.raw;
}

// ===========================================================================
// combine v4: out = f( sum_k T_k @ W_k + bias [+ res] [+ sc @ Wsc] )
// ONE (node,batch) row per thread (round-10 structure: 64 accs, no spill)
// + float4 T-row loads (16B; 32 loads/thread instead of 128 4B loads —
// the round-10 latency stall). FMA accumulation order identical to round 10.
// NOT __restrict__ on T*/res/sc/out: out may alias an input; each thread
// owns its row and reads fully before writing.
// ===========================================================================
template <int CIN, int COUT>
__global__ __launch_bounds__(256) void combine_kernel(
    const __half* T0, const __half* T1, const __half* T2, const __half* T3,
    const float* __restrict__ W, const float* __restrict__ bias,
    const __half* res, const __half* sc, const float* __restrict__ Wsc,
    __half* out, int relu, int V) {
    const int CSC = 32;
    union U4 { float4 raw; __half2 h[4]; };
    int g = blockIdx.x * 256 + threadIdx.x;
    if (g >= V * 8) return;
    int n = g >> 3, b = g & 7;
    size_t ib = (size_t)n * 8 * CIN + (size_t)b * CIN;

    float acc[COUT];
    #pragma unroll
    for (int c = 0; c < COUT; ++c) acc[c] = bias ? bias[c] : 0.f;

    const __half* Ts[4] = {T0, T1, T2, T3};
    #pragma unroll
    for (int k = 0; k < 4; ++k) {
        const float4* rp = (const float4*)(Ts[k] + ib);
        const float* Wk = W + (size_t)k * CIN * COUT;
        #pragma unroll
        for (int c4 = 0; c4 < CIN / 8; ++c4) {
            U4 x; x.raw = rp[c4];
            #pragma unroll
            for (int s = 0; s < 4; ++s) {
                int q = c4 * 4 + s;
                float2 a = __half22float2(x.h[s]);
                const float* w0 = Wk + (2 * q) * COUT;
                const float* w1 = Wk + (2 * q + 1) * COUT;
                #pragma unroll
                for (int c = 0; c < COUT; ++c) {
                    acc[c] = fmaf(a.x, w0[c], acc[c]);
                    acc[c] = fmaf(a.y, w1[c], acc[c]);
                }
            }
        }
    }
    if (sc) {
        const float4* sp = (const float4*)(sc + (size_t)n * 8 * CSC + (size_t)b * CSC);
        #pragma unroll
        for (int c4 = 0; c4 < CSC / 8; ++c4) {
            U4 x; x.raw = sp[c4];
            #pragma unroll
            for (int s = 0; s < 4; ++s) {
                int q = c4 * 4 + s;
                float2 a = __half22float2(x.h[s]);
                const float* w0 = Wsc + (2 * q) * COUT;
                const float* w1 = Wsc + (2 * q + 1) * COUT;
                #pragma unroll
                for (int c = 0; c < COUT; ++c) {
                    acc[c] = fmaf(a.x, w0[c], acc[c]);
                    acc[c] = fmaf(a.y, w1[c], acc[c]);
                }
            }
        }
    }
    size_t ob = (size_t)n * 8 * COUT + (size_t)b * COUT;
    if (res) {
        const __half2* rr = (const __half2*)(res + ob);
        #pragma unroll
        for (int c = 0; c < COUT / 2; ++c) {
            float2 f = __half22float2(rr[c]);
            acc[2 * c] += f.x; acc[2 * c + 1] += f.y;
        }
    }
    if (relu) {
        #pragma unroll
        for (int c = 0; c < COUT; ++c) acc[c] = fmaxf(acc[c], 0.f);
    }
    __half2* ro = (__half2*)(out + ob);
    #pragma unroll
    for (int c = 0; c < COUT / 2; ++c)
        ro[c] = __floats2half2_rn(acc[2 * c], acc[2 * c + 1]);
}

// ===========================================================================
// BatchNorm: two-stage deterministic stats (no float atomics), SB=256 blocks
// ===========================================================================
__global__ void bn_stats_part_kernel(const __half* __restrict__ x, int C, int relu_in,
                                     float* __restrict__ part, size_t N) {
    __shared__ float s_sum[256];
    __shared__ float s_sq[256];
    int t = threadIdx.x;
    size_t i0 = (size_t)blockIdx.x * 256 + t;
    size_t step = (size_t)gridDim.x * 256;
    float s = 0.f, q = 0.f;
    for (size_t i = i0; i < N; i += step) {
        float v = __half2float(x[i]);
        if (relu_in) v = fmaxf(v, 0.f);
        s += v; q += v * v;
    }
    s_sum[t] = s; s_sq[t] = q;
    __syncthreads();
    for (int st = 128; st >= C; st >>= 1) {
        if (t < st) { s_sum[t] += s_sum[t + st]; s_sq[t] += s_sq[t + st]; }
        __syncthreads();
    }
    if (t < C) {
        part[blockIdx.x * 128 + t]     = s_sum[t];
        part[blockIdx.x * 128 + C + t] = s_sq[t];
    }
}

__global__ void bn_reduce_kernel(const float* __restrict__ part, int nblk,
                                 const float* __restrict__ g, const float* __restrict__ be,
                                 float* __restrict__ ss, int C, float invN) {
    int c = threadIdx.x;
    if (c < C) {
        float s = 0.f, q = 0.f;
        for (int b = 0; b < nblk; ++b) {        // fixed order -> deterministic
            s += part[b * 128 + c];
            q += part[b * 128 + C + c];
        }
        float m = s * invN;
        float var = q * invN - m * m;
        float sc = g[c] * rsqrtf(var + 1e-5f);
        ss[c] = sc;
        ss[C + c] = be[c] - m * sc;
    }
}

// in-place: x = f(x)*a + b, f = relu if relu_in  (half2-vectorized)
__global__ void affine_h_kernel(__half* x, const float* __restrict__ ss, int C,
                                int relu_in, size_t N2) {
    size_t stride = (size_t)gridDim.x * blockDim.x;
    __half2* x2 = (__half2*)x;
    for (size_t i = (size_t)blockIdx.x * blockDim.x + threadIdx.x; i < N2; i += stride) {
        int c0 = (int)((2 * i) & (size_t)(C - 1));
        float2 f = __half22float2(x2[i]);
        if (relu_in) { f.x = fmaxf(f.x, 0.f); f.y = fmaxf(f.y, 0.f); }
        f.x = f.x * ss[c0] + ss[C + c0];
        f.y = f.y * ss[c0 + 1] + ss[C + c0 + 1];
        x2[i] = __floats2half2_rn(f.x, f.y);
    }
}

// ===========================================================================
// head: partial max over node slices + int-atomicMax (valid: values >= 0),
// then log_softmax (fp32 out)
// ===========================================================================
__global__ void maxpool_h_kernel(const __half* __restrict__ x, float* pooled, int V, int NS) {
    __shared__ float red[256];
    int o = blockIdx.x % 80;
    int slice = blockIdx.x / 80;
    int v0 = (int)((long long)V * slice / NS);
    int v1 = (int)((long long)V * (slice + 1) / NS);
    float m = 0.f;
    for (int v = v0 + threadIdx.x; v < v1; v += 256)
        m = fmaxf(m, __half2float(x[(size_t)v * 80 + o]));
    red[threadIdx.x] = m;
    __syncthreads();
    for (int st = 128; st > 0; st >>= 1) {
        if (threadIdx.x < st) red[threadIdx.x] = fmaxf(red[threadIdx.x], red[threadIdx.x + st]);
        __syncthreads();
    }
    if (threadIdx.x == 0) atomicMax((int*)&pooled[o], __float_as_int(red[0]));
}

__global__ void lsm_kernel(const float* __restrict__ pooled, float* __restrict__ out) {
    int b = threadIdx.x;
    if (b < 8) {
        float m = -1e30f;
        for (int c = 0; c < 10; ++c) m = fmaxf(m, pooled[b * 10 + c]);
        float s = 0.f;
        for (int c = 0; c < 10; ++c) s += expf(pooled[b * 10 + c] - m);
        float l = logf(s);
        for (int c = 0; c < 10; ++c)
            out[b * 10 + c] = pooled[b * 10 + c] - m - l;
    }
}

__global__ void encode_kernel(float* out, float val) {
    int i = threadIdx.x;
    if (i < 80) out[i] = val;
}

// ===========================================================================
// entry
// ===========================================================================
extern "C" void kernel_launch(void* const* d_in, const int* in_sizes, int n_in,
                              void* d_out, int out_size, void* d_ws, size_t ws_size,
                              hipStream_t stream) {
    (void)in_sizes; (void)n_in; (void)out_size;
    const int V = 50000, E = 800000;
    const int NCH = (V + 255) / 256;
    const int SB = 256;                       // bn stage-1 blocks
    const int NS = 8;                         // maxpool node slices

    auto al = [](size_t x) { return (x + 255) & ~(size_t)255; };
    const size_t FB = al((size_t)V * 512 * sizeof(__half));     // 51.2 MB
    const size_t need = 5 * FB + al((V + 1) * 4) + al(V * 4) + al(E * 4) + al(E * 4)
                      + al((size_t)SB * 128 * 4) + al(8 * 128 * 4) + al(80 * 4) + al(NCH * 4);
    if (ws_size < need) {
        encode_kernel<<<1, 128, 0, stream>>>((float*)d_out, (float)(ws_size >> 20));
        return;
    }

    const float* x_in = (const float*)d_in[0];
    const int* rows   = (const int*)d_in[1];
    const int* colsi  = (const int*)d_in[2];
    const float* lvals = (const float*)d_in[3];
    const float* W_in = (const float*)d_in[4];
    const float* b_in = (const float*)d_in[5];
    const float* g1a = (const float*)d_in[6],  *be1a = (const float*)d_in[7];
    const float* W1a = (const float*)d_in[8],  *b1a  = (const float*)d_in[9];
    const float* g1b = (const float*)d_in[10], *be1b = (const float*)d_in[11];
    const float* W1b = (const float*)d_in[12], *b1b  = (const float*)d_in[13];
    const float* g2a = (const float*)d_in[14], *be2a = (const float*)d_in[15];
    const float* W2a = (const float*)d_in[16], *b2a  = (const float*)d_in[17];
    const float* g2b = (const float*)d_in[18], *be2b = (const float*)d_in[19];
    const float* W2b = (const float*)d_in[20], *b2b  = (const float*)d_in[21];
    const float* W2s = (const float*)d_in[22];
    const float* g3a = (const float*)d_in[23], *be3a = (const float*)d_in[24];
    const float* W3a = (const float*)d_in[25], *b3a  = (const float*)d_in[26];
    const float* g3b = (const float*)d_in[27], *be3b = (const float*)d_in[28];
    const float* W3b = (const float*)d_in[29], *b3b  = (const float*)d_in[30];
    const float* g_o = (const float*)d_in[31], *be_o = (const float*)d_in[32];
    const float* W_o = (const float*)d_in[33], *b_o  = (const float*)d_in[34];

    char* wp = (char*)d_ws;
    auto take = [&](size_t bytes) -> void* { void* p = (void*)wp; wp += al(bytes); return p; };
    __half* P0 = (__half*)take(FB);
    __half* P1 = (__half*)take(FB);
    __half* P2 = (__half*)take(FB);
    __half* P3 = (__half*)take(FB);
    __half* P4 = (__half*)take(FB);
    int* row_ptr  = (int*)take((V + 1) * sizeof(int));
    int* cursor   = (int*)take(V * sizeof(int));
    int* cols_s   = (int*)take(E * sizeof(int));
    float* vals_s = (float*)take(E * sizeof(float));
    float* part   = (float*)take((size_t)SB * 128 * sizeof(float));
    float* aff    = (float*)take(8 * 128 * sizeof(float));
    float* pooled = (float*)take(80 * sizeof(float));
    int* chunks   = (int*)take(NCH * sizeof(int));

    // Launch-state independence: every ws buffer except cursor/pooled is
    // fully written before it is read; cursor needs zeros for hist atomics,
    // pooled needs zeros for atomicMax.
    hipMemsetAsync(cursor, 0, V * sizeof(int), stream);
    hipMemsetAsync(pooled, 0, 80 * sizeof(float), stream);

    // ---- CSR build (+canonical row order) + input transpose ----
    hist_kernel<<<(E + 255) / 256, 256, 0, stream>>>(rows, cursor, E);
    chunk_sum_kernel<<<NCH, 256, 0, stream>>>(cursor, chunks, V);
    scan_chunks_kernel<<<1, 256, 0, stream>>>(chunks, NCH);
    scan_final_kernel<<<NCH, 256, 0, stream>>>(cursor, chunks, row_ptr, V);
    init_cursor_kernel<<<(V + 255) / 256, 256, 0, stream>>>(row_ptr, cursor, V);
    scatter_kernel<<<(E + 255) / 256, 256, 0, stream>>>(rows, colsi, lvals, cursor, cols_s, vals_s, E);
    sort_rows_kernel<<<(V + 255) / 256, 256, 0, stream>>>(row_ptr, cols_s, vals_s, V);
    transpose_in_kernel<<<4096, 256, 0, stream>>>(x_in, P0, V);

    // ---- helpers ----
    auto spmm = [&](const __half* src, __half* dst, const __half* prev, int C) {
        int grid = (V + 3) / 4;
        if (C == 16)
            spmm2_kernel<1><<<grid, 256, 0, stream>>>(row_ptr, cols_s, vals_s,
                (const __half2*)src, (__half2*)dst, (const __half2*)prev, V);
        else if (C == 32)
            spmm2_kernel<2><<<grid, 256, 0, stream>>>(row_ptr, cols_s, vals_s,
                (const __half2*)src, (__half2*)dst, (const __half2*)prev, V);
        else
            spmm2_kernel<4><<<grid, 256, 0, stream>>>(row_ptr, cols_s, vals_s,
                (const __half2*)src, (__half2*)dst, (const __half2*)prev, V);
    };
    const int MG = (V * 8 + 255) / 256;
    auto comb = [&](const __half* T0, const __half* T1, const __half* T2, const __half* T3,
                    int Cin, int Cout, const float* W, const float* bias,
                    const __half* res, const __half* sc, const float* Wsc,
                    __half* out, int relu) {
        if (Cin == 16 && Cout == 32)
            combine_kernel<16, 32><<<MG, 256, 0, stream>>>(T0, T1, T2, T3, W, bias, res, sc, Wsc, out, relu, V);
        else if (Cin == 32 && Cout == 32)
            combine_kernel<32, 32><<<MG, 256, 0, stream>>>(T0, T1, T2, T3, W, bias, res, sc, Wsc, out, relu, V);
        else if (Cin == 32 && Cout == 64)
            combine_kernel<32, 64><<<MG, 256, 0, stream>>>(T0, T1, T2, T3, W, bias, res, sc, Wsc, out, relu, V);
        else if (Cin == 64 && Cout == 64)
            combine_kernel<64, 64><<<MG, 256, 0, stream>>>(T0, T1, T2, T3, W, bias, res, sc, Wsc, out, relu, V);
        else
            combine_kernel<64, 10><<<MG, 256, 0, stream>>>(T0, T1, T2, T3, W, bias, res, sc, Wsc, out, relu, V);
    };
    auto stats = [&](const __half* xb, int C, int relu, int slot, const float* g, const float* be) {
        bn_stats_part_kernel<<<SB, 256, 0, stream>>>(xb, C, relu, part, (size_t)V * 8 * C);
        bn_reduce_kernel<<<1, 64, 0, stream>>>(part, SB, g, be, aff + slot * 128, C,
                                               1.f / ((float)V * 8.f));
    };
    auto affine = [&](__half* xb, int C, int relu, int slot) {
        affine_h_kernel<<<2048, 256, 0, stream>>>(xb, aff + slot * 128, C, relu,
                                                  (size_t)V * 4 * C);
    };
    const __half* NH = nullptr;
    const float*  NF = nullptr;

    // ---- conv_in: x=P0 (16ch) -> relu(cheb+b) -> P4 (32ch) ----
    spmm(P0, P1, nullptr, 16);              // T1
    spmm(P1, P2, P0, 16);                   // T2
    spmm(P2, P3, P1, 16);                   // T3
    comb(P0, P1, P2, P3, 16, 32, W_in, b_in, NH, NH, NF, P4, 1);

    // ---- block 1 (X=P4, 32ch, identity shortcut) ----
    stats(P4, 32, 0, 0, g1a, be1a);
    affine(P4, 32, 0, 0);                   // P4 = xn
    spmm(P4, P0, nullptr, 32);
    spmm(P0, P1, P4, 32);
    spmm(P1, P2, P0, 32);
    comb(P4, P0, P1, P2, 32, 32, W1a, b1a, NH, NH, NF, P0, 0);   // out_a = P0
    stats(P0, 32, 1, 1, g1b, be1b);
    affine(P0, 32, 1, 1);                   // P0 = y
    spmm(P0, P1, nullptr, 32);
    spmm(P1, P2, P0, 32);
    spmm(P2, P3, P1, 32);
    comb(P0, P1, P2, P3, 32, 32, W1b, b1b, P4, NH, NF, P4, 1);   // P4 = block1 out

    // ---- block 2 (X=P4, 32ch -> 64ch, W2s shortcut) ----
    stats(P4, 32, 0, 2, g2a, be2a);
    affine(P4, 32, 0, 2);                   // P4 = xn (32ch)
    spmm(P4, P0, nullptr, 32);
    spmm(P0, P1, P4, 32);
    spmm(P1, P2, P0, 32);
    comb(P4, P0, P1, P2, 32, 64, W2a, b2a, NH, NH, NF, P3, 0);   // out_a = P3 (64ch)
    stats(P3, 64, 1, 3, g2b, be2b);
    affine(P3, 64, 1, 3);                   // P3 = y
    spmm(P3, P0, nullptr, 64);
    spmm(P0, P1, P3, 64);
    spmm(P1, P2, P0, 64);
    comb(P3, P0, P1, P2, 64, 64, W2b, b2b, NH, P4, W2s, P0, 1);  // P0 = block2 out

    // ---- block 3 (X=P0, 64ch, identity shortcut) ----
    stats(P0, 64, 0, 4, g3a, be3a);
    affine(P0, 64, 0, 4);                   // P0 = xn
    spmm(P0, P1, nullptr, 64);
    spmm(P1, P2, P0, 64);
    spmm(P2, P3, P1, 64);
    comb(P0, P1, P2, P3, 64, 64, W3a, b3a, NH, NH, NF, P1, 0);   // out_a = P1
    stats(P1, 64, 1, 5, g3b, be3b);
    affine(P1, 64, 1, 5);                   // P1 = y
    spmm(P1, P2, nullptr, 64);
    spmm(P2, P3, P1, 64);
    spmm(P3, P4, P2, 64);
    comb(P1, P2, P3, P4, 64, 64, W3b, b3b, P0, NH, NF, P1, 1);   // P1 = block3 out

    // ---- head: bn -> relu(cheb 64->10) -> maxpool -> log_softmax ----
    stats(P1, 64, 0, 6, g_o, be_o);
    affine(P1, 64, 0, 6);                   // P1 = bn(x)
    spmm(P1, P0, nullptr, 64);
    spmm(P0, P2, P1, 64);
    spmm(P2, P3, P0, 64);
    comb(P1, P0, P2, P3, 64, 10, W_o, b_o, NH, NH, NF, P4, 1);   // P4 = 80-wide logits
    maxpool_h_kernel<<<80 * NS, 256, 0, stream>>>(P4, pooled, V, NS);
    lsm_kernel<<<1, 64, 0, stream>>>(pooled, (float*)d_out);
}

// Round 13
// 4500.355 us; speedup vs baseline: 1.2975x; 1.0186x over previous
//
#include <hip/hip_runtime.h>
#include <hip/hip_bf16.h>
#include <hip/hip_fp16.h>

// ===========================================================================
// CSR build (multi-block scan; deterministic via per-row sort)
// ===========================================================================
__global__ void hist_kernel(const int* __restrict__ rows, int* __restrict__ counts, int E) {
    int i = blockIdx.x * blockDim.x + threadIdx.x;
    if (i < E) atomicAdd(&counts[rows[i]], 1);
}

__global__ void chunk_sum_kernel(const int* __restrict__ counts, int* __restrict__ chunk_sums, int V) {
    __shared__ int sh[256];
    int t = threadIdx.x;
    int i = blockIdx.x * 256 + t;
    sh[t] = (i < V) ? counts[i] : 0;
    __syncthreads();
    for (int st = 128; st > 0; st >>= 1) {
        if (t < st) sh[t] += sh[t + st];
        __syncthreads();
    }
    if (t == 0) chunk_sums[blockIdx.x] = sh[0];
}

__global__ void scan_chunks_kernel(int* __restrict__ cs, int n) {
    __shared__ int wsum[4];
    int t = threadIdx.x, lane = t & 63, w = t >> 6;
    int orig = (t < n) ? cs[t] : 0;
    int x = orig;
    #pragma unroll
    for (int d = 1; d < 64; d <<= 1) {
        int y = __shfl_up(x, d);
        if (lane >= d) x += y;
    }
    if (lane == 63) wsum[w] = x;
    __syncthreads();
    int wo = 0;
    for (int j = 0; j < w; ++j) wo += wsum[j];
    if (t < n) cs[t] = wo + x - orig;     // exclusive
}

__global__ void scan_final_kernel(const int* __restrict__ counts, const int* __restrict__ chunk_off,
                                  int* __restrict__ row_ptr, int V) {
    __shared__ int wsum[4];
    int t = threadIdx.x, lane = t & 63, w = t >> 6;
    int i = blockIdx.x * 256 + t;
    int x = (i < V) ? counts[i] : 0;
    #pragma unroll
    for (int d = 1; d < 64; d <<= 1) {
        int y = __shfl_up(x, d);
        if (lane >= d) x += y;
    }
    if (lane == 63) wsum[w] = x;
    __syncthreads();
    int wo = 0;
    for (int j = 0; j < w; ++j) wo += wsum[j];
    if (i < V) row_ptr[i + 1] = chunk_off[blockIdx.x] + wo + x;
    if (i == 0) row_ptr[0] = 0;
}

__global__ void init_cursor_kernel(const int* __restrict__ row_ptr, int* __restrict__ cursor, int V) {
    int i = blockIdx.x * blockDim.x + threadIdx.x;
    if (i < V) cursor[i] = row_ptr[i];
}

__global__ void scatter_kernel(const int* __restrict__ rows, const int* __restrict__ cols,
                               const float* __restrict__ vals, int* __restrict__ cursor,
                               int* __restrict__ cols_s, float* __restrict__ vals_s, int E) {
    int i = blockIdx.x * blockDim.x + threadIdx.x;
    if (i < E) {
        int r = rows[i];
        int p = atomicAdd(&cursor[r], 1);
        cols_s[p] = cols[i];
        vals_s[p] = vals[i];
    }
}

// canonical per-row order: insertion sort by (col, val-bits). Makes CSR
// bitwise-deterministic regardless of scatter's atomic ordering.
__global__ void sort_rows_kernel(const int* __restrict__ row_ptr, int* cols, float* vals, int V) {
    int v = blockIdx.x * blockDim.x + threadIdx.x;
    if (v >= V) return;
    int e0 = row_ptr[v], e1 = row_ptr[v + 1];
    for (int i = e0 + 1; i < e1; ++i) {
        int c = cols[i];
        unsigned xb = __float_as_uint(vals[i]);
        int j = i - 1;
        while (j >= e0) {
            int cj = cols[j];
            unsigned vj = __float_as_uint(vals[j]);
            if (cj > c || (cj == c && vj > xb)) {
                cols[j + 1] = cj; vals[j + 1] = __uint_as_float(vj);
                --j;
            } else break;
        }
        cols[j + 1] = c;
        vals[j + 1] = __uint_as_float(xb);
    }
}

// ===========================================================================
// transpose input (B,16,V) fp32 -> (V, B*16) fp16
// ===========================================================================
__global__ void transpose_in_kernel(const float* __restrict__ x, __half* __restrict__ X, int V) {
    int total = V * 128;
    for (int i = blockIdx.x * blockDim.x + threadIdx.x; i < total; i += gridDim.x * blockDim.x) {
        int v = i >> 7;
        int t = i & 127;          // t = b*16 + c
        X[i] = __float2half(x[t * V + v]);
    }
}

// ===========================================================================
// SpMM: one wave per node, lane owns VPT half2, unroll 8.
//   dst[v,:] = sum_e vals[e]*src[cols[e],:]        (prev == null)
//   dst[v,:] = 2*that - prev[v,:]                  (prev != null)
// dst always distinct from src/prev in the schedule.
// ===========================================================================
template <int VPT> struct PackT;
template <> struct PackT<1> { using T = float;  };
template <> struct PackT<2> { using T = float2; };
template <> struct PackT<4> { using T = float4; };

template <int VPT>
__global__ __launch_bounds__(256) void spmm2_kernel(
    const int* __restrict__ row_ptr, const int* __restrict__ cols,
    const float* __restrict__ vals, const __half2* __restrict__ src,
    __half2* dst, const __half2* prev, int V) {
    using T = typename PackT<VPT>::T;
    union U { T raw; __half2 h[VPT]; };
    int lane = threadIdx.x & 63;
    int v = (blockIdx.x << 2) | (threadIdx.x >> 6);
    if (v >= V) return;
    const int W = VPT * 64;
    const size_t row = (size_t)v * W + lane * VPT;

    float pr[2 * VPT];
    bool hasp = (prev != nullptr);
    if (hasp) {
        U pv; pv.raw = *(const T*)(prev + row);
        #pragma unroll
        for (int j = 0; j < VPT; ++j) {
            float2 f = __half22float2(pv.h[j]);
            pr[2 * j] = f.x; pr[2 * j + 1] = f.y;
        }
    }
    float acc[2 * VPT];
    #pragma unroll
    for (int j = 0; j < 2 * VPT; ++j) acc[j] = 0.f;

    int e0 = row_ptr[v], e1 = row_ptr[v + 1];
    int e = e0;
    for (; e + 8 <= e1; e += 8) {
        int   c[8]; float w[8]; U g[8];
        #pragma unroll
        for (int k = 0; k < 8; ++k) { c[k] = cols[e + k]; w[k] = vals[e + k]; }
        #pragma unroll
        for (int k = 0; k < 8; ++k)
            g[k].raw = *(const T*)(src + (size_t)c[k] * W + lane * VPT);
        #pragma unroll
        for (int k = 0; k < 8; ++k) {
            #pragma unroll
            for (int j = 0; j < VPT; ++j) {
                float2 f = __half22float2(g[k].h[j]);
                acc[2*j] += w[k] * f.x; acc[2*j+1] += w[k] * f.y;
            }
        }
    }
    for (; e + 4 <= e1; e += 4) {
        int   c[4]; float w[4]; U g[4];
        #pragma unroll
        for (int k = 0; k < 4; ++k) { c[k] = cols[e + k]; w[k] = vals[e + k]; }
        #pragma unroll
        for (int k = 0; k < 4; ++k)
            g[k].raw = *(const T*)(src + (size_t)c[k] * W + lane * VPT);
        #pragma unroll
        for (int k = 0; k < 4; ++k) {
            #pragma unroll
            for (int j = 0; j < VPT; ++j) {
                float2 f = __half22float2(g[k].h[j]);
                acc[2*j] += w[k] * f.x; acc[2*j+1] += w[k] * f.y;
            }
        }
    }
    for (; e < e1; ++e) {
        int c = cols[e]; float wv = vals[e];
        U g; g.raw = *(const T*)(src + (size_t)c * W + lane * VPT);
        #pragma unroll
        for (int j = 0; j < VPT; ++j) {
            float2 f = __half22float2(g.h[j]);
            acc[2*j] += wv * f.x; acc[2*j+1] += wv * f.y;
        }
    }
    if (hasp) {
        #pragma unroll
        for (int j = 0; j < 2 * VPT; ++j) acc[j] = 2.f * acc[j] - pr[j];
    }
    U o;
    #pragma unroll
    for (int j = 0; j < VPT; ++j) o.h[j] = __floats2half2_rn(acc[2*j], acc[2*j+1]);
    *(T*)(dst + row) = o.raw;
}

// ===========================================================================
// combine v5: out = f( sum_k T_k @ W_k + bias [+ res] [+ sc @ Wsc] )
// One (node,batch) row per thread, 64 fp32 accs (no spill, round-12 proven),
// float4 T loads. Key round-13 change: the c4 loop is NOT unrolled
// (#pragma unroll 1) so the hot body (~4 s-steps) stays I$-resident —
// round 12's full unroll produced ~130KB of code vs 32KB I$ (VALUBusy 17%).
// FMA accumulation order identical to rounds 10/12 (bitwise-stable).
// NOT __restrict__ on T*/res/sc/out: out may alias an input; each thread
// owns its row and reads fully before writing.
// ===========================================================================
template <int CIN, int COUT>
__global__ __launch_bounds__(256) void combine_kernel(
    const __half* T0, const __half* T1, const __half* T2, const __half* T3,
    const float* __restrict__ W, const float* __restrict__ bias,
    const __half* res, const __half* sc, const float* __restrict__ Wsc,
    __half* out, int relu, int V) {
    const int CSC = 32;
    union U4 { float4 raw; __half2 h[4]; };
    int g = blockIdx.x * 256 + threadIdx.x;
    if (g >= V * 8) return;
    int n = g >> 3, b = g & 7;
    size_t ib = (size_t)n * 8 * CIN + (size_t)b * CIN;

    float acc[COUT];
    #pragma unroll
    for (int c = 0; c < COUT; ++c) acc[c] = bias ? bias[c] : 0.f;

    const __half* Ts[4] = {T0, T1, T2, T3};
    #pragma unroll
    for (int k = 0; k < 4; ++k) {
        const float4* rp = (const float4*)(Ts[k] + ib);
        const float* Wk = W + (size_t)k * CIN * COUT;
        #pragma unroll 1
        for (int c4 = 0; c4 < CIN / 8; ++c4) {
            U4 x; x.raw = rp[c4];
            #pragma unroll
            for (int s = 0; s < 4; ++s) {
                int q = c4 * 4 + s;
                float2 a = __half22float2(x.h[s]);
                const float* w0 = Wk + (2 * q) * COUT;
                const float* w1 = Wk + (2 * q + 1) * COUT;
                #pragma unroll
                for (int c = 0; c < COUT; ++c) {
                    acc[c] = fmaf(a.x, w0[c], acc[c]);
                    acc[c] = fmaf(a.y, w1[c], acc[c]);
                }
            }
        }
    }
    if (sc) {
        const float4* sp = (const float4*)(sc + (size_t)n * 8 * CSC + (size_t)b * CSC);
        #pragma unroll 1
        for (int c4 = 0; c4 < CSC / 8; ++c4) {
            U4 x; x.raw = sp[c4];
            #pragma unroll
            for (int s = 0; s < 4; ++s) {
                int q = c4 * 4 + s;
                float2 a = __half22float2(x.h[s]);
                const float* w0 = Wsc + (2 * q) * COUT;
                const float* w1 = Wsc + (2 * q + 1) * COUT;
                #pragma unroll
                for (int c = 0; c < COUT; ++c) {
                    acc[c] = fmaf(a.x, w0[c], acc[c]);
                    acc[c] = fmaf(a.y, w1[c], acc[c]);
                }
            }
        }
    }
    size_t ob = (size_t)n * 8 * COUT + (size_t)b * COUT;
    if (res) {
        const __half2* rr = (const __half2*)(res + ob);
        #pragma unroll
        for (int c = 0; c < COUT / 2; ++c) {
            float2 f = __half22float2(rr[c]);
            acc[2 * c] += f.x; acc[2 * c + 1] += f.y;
        }
    }
    if (relu) {
        #pragma unroll
        for (int c = 0; c < COUT; ++c) acc[c] = fmaxf(acc[c], 0.f);
    }
    __half2* ro = (__half2*)(out + ob);
    #pragma unroll
    for (int c = 0; c < COUT / 2; ++c)
        ro[c] = __floats2half2_rn(acc[2 * c], acc[2 * c + 1]);
}

// ===========================================================================
// BatchNorm: two-stage deterministic stats (no float atomics), SB=256.
// Stage 1 reads half2 pairs; thread t's pair channels are (2t mod C, 2t+1
// mod C) fixed (since C | 512), so reduce even/odd sums down to C/2 threads.
// ===========================================================================
__global__ void bn_stats_part_kernel(const __half2* __restrict__ x2, int C, int relu_in,
                                     float* __restrict__ part, size_t N2) {
    __shared__ float sx[256], qx[256], sy[256], qy[256];
    int t = threadIdx.x;
    size_t i0 = (size_t)blockIdx.x * 256 + t;
    size_t step = (size_t)gridDim.x * 256;
    float ax = 0.f, aqx = 0.f, ay = 0.f, aqy = 0.f;
    for (size_t i = i0; i < N2; i += step) {
        float2 f = __half22float2(x2[i]);
        if (relu_in) { f.x = fmaxf(f.x, 0.f); f.y = fmaxf(f.y, 0.f); }
        ax += f.x; aqx += f.x * f.x;
        ay += f.y; aqy += f.y * f.y;
    }
    sx[t] = ax; qx[t] = aqx; sy[t] = ay; qy[t] = aqy;
    __syncthreads();
    int half = C >> 1;
    for (int st = 128; st >= half; st >>= 1) {
        if (t < st) {
            sx[t] += sx[t + st]; qx[t] += qx[t + st];
            sy[t] += sy[t + st]; qy[t] += qy[t + st];
        }
        __syncthreads();
    }
    if (t < half) {
        part[blockIdx.x * 128 + 2 * t]         = sx[t];
        part[blockIdx.x * 128 + 2 * t + 1]     = sy[t];
        part[blockIdx.x * 128 + C + 2 * t]     = qx[t];
        part[blockIdx.x * 128 + C + 2 * t + 1] = qy[t];
    }
}

__global__ void bn_reduce_kernel(const float* __restrict__ part, int nblk,
                                 const float* __restrict__ g, const float* __restrict__ be,
                                 float* __restrict__ ss, int C, float invN) {
    int c = threadIdx.x;
    if (c < C) {
        float s = 0.f, q = 0.f;
        for (int b = 0; b < nblk; ++b) {        // fixed order -> deterministic
            s += part[b * 128 + c];
            q += part[b * 128 + C + c];
        }
        float m = s * invN;
        float var = q * invN - m * m;
        float sc = g[c] * rsqrtf(var + 1e-5f);
        ss[c] = sc;
        ss[C + c] = be[c] - m * sc;
    }
}

// in-place: x = f(x)*a + b, f = relu if relu_in  (half2-vectorized)
__global__ void affine_h_kernel(__half* x, const float* __restrict__ ss, int C,
                                int relu_in, size_t N2) {
    size_t stride = (size_t)gridDim.x * blockDim.x;
    __half2* x2 = (__half2*)x;
    for (size_t i = (size_t)blockIdx.x * blockDim.x + threadIdx.x; i < N2; i += stride) {
        int c0 = (int)((2 * i) & (size_t)(C - 1));
        float2 f = __half22float2(x2[i]);
        if (relu_in) { f.x = fmaxf(f.x, 0.f); f.y = fmaxf(f.y, 0.f); }
        f.x = f.x * ss[c0] + ss[C + c0];
        f.y = f.y * ss[c0 + 1] + ss[C + c0 + 1];
        x2[i] = __floats2half2_rn(f.x, f.y);
    }
}

// ===========================================================================
// head: partial max over node slices + int-atomicMax (valid: values >= 0),
// then log_softmax (fp32 out)
// ===========================================================================
__global__ void maxpool_h_kernel(const __half* __restrict__ x, float* pooled, int V, int NS) {
    __shared__ float red[256];
    int o = blockIdx.x % 80;
    int slice = blockIdx.x / 80;
    int v0 = (int)((long long)V * slice / NS);
    int v1 = (int)((long long)V * (slice + 1) / NS);
    float m = 0.f;
    for (int v = v0 + threadIdx.x; v < v1; v += 256)
        m = fmaxf(m, __half2float(x[(size_t)v * 80 + o]));
    red[threadIdx.x] = m;
    __syncthreads();
    for (int st = 128; st > 0; st >>= 1) {
        if (threadIdx.x < st) red[threadIdx.x] = fmaxf(red[threadIdx.x], red[threadIdx.x + st]);
        __syncthreads();
    }
    if (threadIdx.x == 0) atomicMax((int*)&pooled[o], __float_as_int(red[0]));
}

__global__ void lsm_kernel(const float* __restrict__ pooled, float* __restrict__ out) {
    int b = threadIdx.x;
    if (b < 8) {
        float m = -1e30f;
        for (int c = 0; c < 10; ++c) m = fmaxf(m, pooled[b * 10 + c]);
        float s = 0.f;
        for (int c = 0; c < 10; ++c) s += expf(pooled[b * 10 + c] - m);
        float l = logf(s);
        for (int c = 0; c < 10; ++c)
            out[b * 10 + c] = pooled[b * 10 + c] - m - l;
    }
}

__global__ void encode_kernel(float* out, float val) {
    int i = threadIdx.x;
    if (i < 80) out[i] = val;
}

// ===========================================================================
// entry
// ===========================================================================
extern "C" void kernel_launch(void* const* d_in, const int* in_sizes, int n_in,
                              void* d_out, int out_size, void* d_ws, size_t ws_size,
                              hipStream_t stream) {
    (void)in_sizes; (void)n_in; (void)out_size;
    const int V = 50000, E = 800000;
    const int NCH = (V + 255) / 256;
    const int SB = 256;                       // bn stage-1 blocks
    const int NS = 8;                         // maxpool node slices

    auto al = [](size_t x) { return (x + 255) & ~(size_t)255; };
    const size_t FB = al((size_t)V * 512 * sizeof(__half));     // 51.2 MB
    const size_t need = 5 * FB + al((V + 1) * 4) + al(V * 4) + al(E * 4) + al(E * 4)
                      + al((size_t)SB * 128 * 4) + al(8 * 128 * 4) + al(80 * 4) + al(NCH * 4);
    if (ws_size < need) {
        encode_kernel<<<1, 128, 0, stream>>>((float*)d_out, (float)(ws_size >> 20));
        return;
    }

    const float* x_in = (const float*)d_in[0];
    const int* rows   = (const int*)d_in[1];
    const int* colsi  = (const int*)d_in[2];
    const float* lvals = (const float*)d_in[3];
    const float* W_in = (const float*)d_in[4];
    const float* b_in = (const float*)d_in[5];
    const float* g1a = (const float*)d_in[6],  *be1a = (const float*)d_in[7];
    const float* W1a = (const float*)d_in[8],  *b1a  = (const float*)d_in[9];
    const float* g1b = (const float*)d_in[10], *be1b = (const float*)d_in[11];
    const float* W1b = (const float*)d_in[12], *b1b  = (const float*)d_in[13];
    const float* g2a = (const float*)d_in[14], *be2a = (const float*)d_in[15];
    const float* W2a = (const float*)d_in[16], *b2a  = (const float*)d_in[17];
    const float* g2b = (const float*)d_in[18], *be2b = (const float*)d_in[19];
    const float* W2b = (const float*)d_in[20], *b2b  = (const float*)d_in[21];
    const float* W2s = (const float*)d_in[22];
    const float* g3a = (const float*)d_in[23], *be3a = (const float*)d_in[24];
    const float* W3a = (const float*)d_in[25], *b3a  = (const float*)d_in[26];
    const float* g3b = (const float*)d_in[27], *be3b = (const float*)d_in[28];
    const float* W3b = (const float*)d_in[29], *b3b  = (const float*)d_in[30];
    const float* g_o = (const float*)d_in[31], *be_o = (const float*)d_in[32];
    const float* W_o = (const float*)d_in[33], *b_o  = (const float*)d_in[34];

    char* wp = (char*)d_ws;
    auto take = [&](size_t bytes) -> void* { void* p = (void*)wp; wp += al(bytes); return p; };
    __half* P0 = (__half*)take(FB);
    __half* P1 = (__half*)take(FB);
    __half* P2 = (__half*)take(FB);
    __half* P3 = (__half*)take(FB);
    __half* P4 = (__half*)take(FB);
    int* row_ptr  = (int*)take((V + 1) * sizeof(int));
    int* cursor   = (int*)take(V * sizeof(int));
    int* cols_s   = (int*)take(E * sizeof(int));
    float* vals_s = (float*)take(E * sizeof(float));
    float* part   = (float*)take((size_t)SB * 128 * sizeof(float));
    float* aff    = (float*)take(8 * 128 * sizeof(float));
    float* pooled = (float*)take(80 * sizeof(float));
    int* chunks   = (int*)take(NCH * sizeof(int));

    // Launch-state independence: every ws buffer except cursor/pooled is
    // fully written before it is read; cursor needs zeros for hist atomics,
    // pooled needs zeros for atomicMax.
    hipMemsetAsync(cursor, 0, V * sizeof(int), stream);
    hipMemsetAsync(pooled, 0, 80 * sizeof(float), stream);

    // ---- CSR build (+canonical row order) + input transpose ----
    hist_kernel<<<(E + 255) / 256, 256, 0, stream>>>(rows, cursor, E);
    chunk_sum_kernel<<<NCH, 256, 0, stream>>>(cursor, chunks, V);
    scan_chunks_kernel<<<1, 256, 0, stream>>>(chunks, NCH);
    scan_final_kernel<<<NCH, 256, 0, stream>>>(cursor, chunks, row_ptr, V);
    init_cursor_kernel<<<(V + 255) / 256, 256, 0, stream>>>(row_ptr, cursor, V);
    scatter_kernel<<<(E + 255) / 256, 256, 0, stream>>>(rows, colsi, lvals, cursor, cols_s, vals_s, E);
    sort_rows_kernel<<<(V + 255) / 256, 256, 0, stream>>>(row_ptr, cols_s, vals_s, V);
    transpose_in_kernel<<<4096, 256, 0, stream>>>(x_in, P0, V);

    // ---- helpers ----
    auto spmm = [&](const __half* src, __half* dst, const __half* prev, int C) {
        int grid = (V + 3) / 4;
        if (C == 16)
            spmm2_kernel<1><<<grid, 256, 0, stream>>>(row_ptr, cols_s, vals_s,
                (const __half2*)src, (__half2*)dst, (const __half2*)prev, V);
        else if (C == 32)
            spmm2_kernel<2><<<grid, 256, 0, stream>>>(row_ptr, cols_s, vals_s,
                (const __half2*)src, (__half2*)dst, (const __half2*)prev, V);
        else
            spmm2_kernel<4><<<grid, 256, 0, stream>>>(row_ptr, cols_s, vals_s,
                (const __half2*)src, (__half2*)dst, (const __half2*)prev, V);
    };
    const int MG = (V * 8 + 255) / 256;
    auto comb = [&](const __half* T0, const __half* T1, const __half* T2, const __half* T3,
                    int Cin, int Cout, const float* W, const float* bias,
                    const __half* res, const __half* sc, const float* Wsc,
                    __half* out, int relu) {
        if (Cin == 16 && Cout == 32)
            combine_kernel<16, 32><<<MG, 256, 0, stream>>>(T0, T1, T2, T3, W, bias, res, sc, Wsc, out, relu, V);
        else if (Cin == 32 && Cout == 32)
            combine_kernel<32, 32><<<MG, 256, 0, stream>>>(T0, T1, T2, T3, W, bias, res, sc, Wsc, out, relu, V);
        else if (Cin == 32 && Cout == 64)
            combine_kernel<32, 64><<<MG, 256, 0, stream>>>(T0, T1, T2, T3, W, bias, res, sc, Wsc, out, relu, V);
        else if (Cin == 64 && Cout == 64)
            combine_kernel<64, 64><<<MG, 256, 0, stream>>>(T0, T1, T2, T3, W, bias, res, sc, Wsc, out, relu, V);
        else
            combine_kernel<64, 10><<<MG, 256, 0, stream>>>(T0, T1, T2, T3, W, bias, res, sc, Wsc, out, relu, V);
    };
    auto stats = [&](const __half* xb, int C, int relu, int slot, const float* g, const float* be) {
        bn_stats_part_kernel<<<SB, 256, 0, stream>>>((const __half2*)xb, C, relu, part,
                                                     (size_t)V * 4 * C);
        bn_reduce_kernel<<<1, 64, 0, stream>>>(part, SB, g, be, aff + slot * 128, C,
                                               1.f / ((float)V * 8.f));
    };
    auto affine = [&](__half* xb, int C, int relu, int slot) {
        affine_h_kernel<<<2048, 256, 0, stream>>>(xb, aff + slot * 128, C, relu,
                                                  (size_t)V * 4 * C);
    };
    const __half* NH = nullptr;
    const float*  NF = nullptr;

    // ---- conv_in: x=P0 (16ch) -> relu(cheb+b) -> P4 (32ch) ----
    spmm(P0, P1, nullptr, 16);              // T1
    spmm(P1, P2, P0, 16);                   // T2
    spmm(P2, P3, P1, 16);                   // T3
    comb(P0, P1, P2, P3, 16, 32, W_in, b_in, NH, NH, NF, P4, 1);

    // ---- block 1 (X=P4, 32ch, identity shortcut) ----
    stats(P4, 32, 0, 0, g1a, be1a);
    affine(P4, 32, 0, 0);                   // P4 = xn
    spmm(P4, P0, nullptr, 32);
    spmm(P0, P1, P4, 32);
    spmm(P1, P2, P0, 32);
    comb(P4, P0, P1, P2, 32, 32, W1a, b1a, NH, NH, NF, P0, 0);   // out_a = P0
    stats(P0, 32, 1, 1, g1b, be1b);
    affine(P0, 32, 1, 1);                   // P0 = y
    spmm(P0, P1, nullptr, 32);
    spmm(P1, P2, P0, 32);
    spmm(P2, P3, P1, 32);
    comb(P0, P1, P2, P3, 32, 32, W1b, b1b, P4, NH, NF, P4, 1);   // P4 = block1 out

    // ---- block 2 (X=P4, 32ch -> 64ch, W2s shortcut) ----
    stats(P4, 32, 0, 2, g2a, be2a);
    affine(P4, 32, 0, 2);                   // P4 = xn (32ch)
    spmm(P4, P0, nullptr, 32);
    spmm(P0, P1, P4, 32);
    spmm(P1, P2, P0, 32);
    comb(P4, P0, P1, P2, 32, 64, W2a, b2a, NH, NH, NF, P3, 0);   // out_a = P3 (64ch)
    stats(P3, 64, 1, 3, g2b, be2b);
    affine(P3, 64, 1, 3);                   // P3 = y
    spmm(P3, P0, nullptr, 64);
    spmm(P0, P1, P3, 64);
    spmm(P1, P2, P0, 64);
    comb(P3, P0, P1, P2, 64, 64, W2b, b2b, NH, P4, W2s, P0, 1);  // P0 = block2 out

    // ---- block 3 (X=P0, 64ch, identity shortcut) ----
    stats(P0, 64, 0, 4, g3a, be3a);
    affine(P0, 64, 0, 4);                   // P0 = xn
    spmm(P0, P1, nullptr, 64);
    spmm(P1, P2, P0, 64);
    spmm(P2, P3, P1, 64);
    comb(P0, P1, P2, P3, 64, 64, W3a, b3a, NH, NH, NF, P1, 0);   // out_a = P1
    stats(P1, 64, 1, 5, g3b, be3b);
    affine(P1, 64, 1, 5);                   // P1 = y
    spmm(P1, P2, nullptr, 64);
    spmm(P2, P3, P1, 64);
    spmm(P3, P4, P2, 64);
    comb(P1, P2, P3, P4, 64, 64, W3b, b3b, P0, NH, NF, P1, 1);   // P1 = block3 out

    // ---- head: bn -> relu(cheb 64->10) -> maxpool -> log_softmax ----
    stats(P1, 64, 0, 6, g_o, be_o);
    affine(P1, 64, 0, 6);                   // P1 = bn(x)
    spmm(P1, P0, nullptr, 64);
    spmm(P0, P2, P1, 64);
    spmm(P2, P3, P0, 64);
    comb(P1, P0, P2, P3, 64, 10, W_o, b_o, NH, NH, NF, P4, 1);   // P4 = 80-wide logits
    maxpool_h_kernel<<<80 * NS, 256, 0, stream>>>(P4, pooled, V, NS);
    lsm_kernel<<<1, 64, 0, stream>>>(pooled, (float*)d_out);
}